// Round 8
// baseline (225.253 us; speedup 1.0000x reference)
//
#include <hip/hip_runtime.h>
#include <math.h>

#define BN_ 8
#define CIN 256
#define COUT 256
#define HH 64
#define WW 64
#define HW 4096
#define KK 9
#define OC 18
#define EPS 1e-5f
#define NTOT (BN_ * COUT * HW)

// ws layout (float units):
//   off_ws: [B][18][HW]                 = 589824 floats
//   wTb:    bf16 [72][4][256][8] shorts = 294912 floats (main GEMM A image)
//   wob:    bf16 [72][4][32][8] shorts  = 36864 floats  (offset-conv A image)
//   stats:  [2][COUT]                   = 512 floats
//   xt:     bf16 [B][32][HW][8] shorts  = 4194304 floats (g8-planar x: pixel stride 16B)
// Grid-barrier counter: lives in wob's zero padding (ki=71, m=31 rows) —
// re-zeroed by prep every launch, dead during gemm, never overwritten.
#define OFF_WS 0
#define WTB_WS 589824
#define WOB_WS 884736
#define ST_WS  921600
#define XT_WS  922112

typedef float f32x4 __attribute__((ext_vector_type(4)));
typedef float f32x2 __attribute__((ext_vector_type(2)));
typedef short s16x8 __attribute__((ext_vector_type(8)));
typedef unsigned int u32x4 __attribute__((ext_vector_type(4)));

__device__ __forceinline__ unsigned short f2bf(float f) {
  unsigned int u = __float_as_uint(f);
  unsigned int r = (u + 0x7fffu + ((u >> 16) & 1u)) >> 16;  // RNE
  return (unsigned short)r;
}
__device__ __forceinline__ float bf2f(short s) {
  return __uint_as_float(((unsigned int)(unsigned short)s) << 16);
}

// ---------------- Kernel T: transpose x -> xt[b][g8][p][8] bf16 ----------------
__global__ __launch_bounds__(256) void xpose_kernel(
    const float* __restrict__ x, unsigned short* __restrict__ xt) {
  __shared__ float s[64][65];
  const int t = threadIdx.x;
  const int p0 = blockIdx.x * 64;
  const int c0 = blockIdx.y * 64;
  const int b  = blockIdx.z;
  const float* xb = x + ((size_t)b * CIN + c0) * HW + p0;
#pragma unroll
  for (int pass = 0; pass < 4; ++pass) {
    int cr = pass * 16 + (t >> 4);
    int ps = (t & 15) * 4;
    float4 v = *(const float4*)(xb + (size_t)cr * HW + ps);
    s[ps + 0][cr] = v.x; s[ps + 1][cr] = v.y; s[ps + 2][cr] = v.z; s[ps + 3][cr] = v.w;
  }
  __syncthreads();
  unsigned short* xo = xt + (size_t)b * 32 * HW * 8;
#pragma unroll
  for (int r = 0; r < 2; ++r) {
    int flat = r * 256 + t;
    int pr = flat >> 3, sub = flat & 7;
    int g8 = (c0 >> 3) + sub;
    s16x8 v;
#pragma unroll
    for (int j = 0; j < 8; ++j) v[j] = (short)f2bf(s[pr][sub * 8 + j]);
    *(s16x8*)(xo + ((size_t)g8 * HW + p0 + pr) * 8) = v;
  }
}

// ---------------- Kernel P: pack w_off + w, zero stats (merged prep) ----------------
__global__ __launch_bounds__(256) void prep_kernel(
    const float* __restrict__ w_off, const float* __restrict__ w,
    unsigned short* __restrict__ wob, unsigned short* __restrict__ wTb,
    float* __restrict__ stats) {
  const int kb = blockIdx.x;          // 0..71
  const int kk = kb >> 3;
  const int c0 = (kb & 7) << 5;
  const int t = threadIdx.x;
  if (kb == 71) { stats[t] = 0.f; stats[256 + t] = 0.f; }
  // w_off pack (M=32 pad; m>=18 rows are zeros -> also the grid-barrier word)
#pragma unroll
  for (int r = 0; r < 4; ++r) {
    int e = r * 256 + t;              // g*256 + m*8 + j
    int g = e >> 8, m = (e >> 3) & 31, j = e & 7;
    int c = c0 + g * 8 + j;
    unsigned short v = 0;
    if (m < OC) v = f2bf(w_off[((size_t)m * CIN + c) * 9 + kk]);
    wob[(size_t)kb * 1024 + e] = v;
  }
  // w pack (k-major)
#pragma unroll
  for (int g = 0; g < 4; ++g)
#pragma unroll
    for (int j = 0; j < 8; ++j) {
      int c = c0 + g * 8 + j;
      wTb[(((size_t)kb * 4 + g) * 256 + t) * 8 + j] =
          f2bf(w[((size_t)t * CIN + c) * 9 + kk]);
    }
}

// ---------------- Kernel A: offset conv as MFMA GEMM, 2-deep pipelined ----------------
// Prefetch step s+1's 4 gathers + A-frags into registers while step s's MFMA
// runs (was fully serial: load -> waitcnt(0) -> MFMA, 18 exposed L2 trips).
// Same-wave DS ops execute in order, so ds_write(s) -> ds_read(s) needs no
// explicit wait, and ds_write(s+1) cannot pass ds_read(s).
__global__ __launch_bounds__(256) void offset_kernel(
    const unsigned short* __restrict__ xt, const unsigned short* __restrict__ wob,
    const float* __restrict__ b_off, float* __restrict__ off_ws) {
  __shared__ __align__(16) char smem[32768];
  const int t = threadIdx.x;
  const int lane = t & 63;
  const int wv = t >> 6;
  const int b = blockIdx.x & 7;
  const int h = blockIdx.x >> 3;
  const unsigned short* xtb = xt + (size_t)b * 32 * HW * 8;
  const int fr = lane & 15, fq = lane >> 4;
  unsigned short* sb = (unsigned short*)smem + wv * 2048;
  float* red = (float*)smem;

  f32x4 acc[2][4] = {};

  auto fetch = [&](int s, s16x8* V, s16x8* AF) {
    const int ki = wv * 18 + s;
    const int kk = ki >> 3, cc0g = (ki & 7) << 2;   // plane base = (ki&7)*4
    const int ky = kk / 3 - 1, kx = kk % 3 - 1;
    const int y = h + ky;
    const int xcol = lane + kx;
    const bool ok = (y >= 0) && (y < HH) && (xcol >= 0) && (xcol < WW);
    const int pix = y * WW + xcol;
#pragma unroll
    for (int g = 0; g < 4; ++g) {
      s16x8 v = {0, 0, 0, 0, 0, 0, 0, 0};
      if (ok)
        __builtin_memcpy(&v, (const char*)xtb + (((size_t)(cc0g + g)) << 16) + (size_t)pix * 16, 16);
      V[g] = v;
    }
    const unsigned short* ap = wob + (size_t)ki * 1024;
#pragma unroll
    for (int i = 0; i < 2; ++i)
      AF[i] = *(const s16x8*)&ap[(fq * 32 + i * 16 + fr) * 8];
  };

  s16x8 VE[4], VO[4], afE[2], afO[2];
  fetch(0, VE, afE);

#define OBODY(S, VC, VN, AFC, AFN)                                             \
  {                                                                            \
    _Pragma("unroll")                                                          \
    for (int g = 0; g < 4; ++g)                                                \
      *(s16x8*)&sb[(g * 64 + lane) * 8] = VC[g];                               \
    if ((S) + 1 < 18) fetch((S) + 1, VN, AFN);                                 \
    s16x8 bf[4];                                                               \
    _Pragma("unroll")                                                          \
    for (int jn = 0; jn < 4; ++jn)                                             \
      bf[jn] = *(const s16x8*)&sb[(fq * 64 + jn * 16 + fr) * 8];               \
    _Pragma("unroll")                                                          \
    for (int i = 0; i < 2; ++i)                                                \
      _Pragma("unroll")                                                        \
      for (int jn = 0; jn < 4; ++jn)                                           \
        acc[i][jn] = __builtin_amdgcn_mfma_f32_16x16x32_bf16(                  \
            AFC[i], bf[jn], acc[i][jn], 0, 0, 0);                              \
  }

  for (int sp = 0; sp < 9; ++sp) {
    OBODY(2 * sp, VE, VO, afE, afO)
    OBODY(2 * sp + 1, VO, VE, afO, afE)
  }
#undef OBODY

  __syncthreads();
#pragma unroll
  for (int i = 0; i < 2; ++i)
#pragma unroll
    for (int jn = 0; jn < 4; ++jn)
#pragma unroll
      for (int rg = 0; rg < 4; ++rg)
        red[wv * 2048 + (i * 16 + fq * 4 + rg) * 64 + jn * 16 + fr] = acc[i][jn][rg];
  __syncthreads();

  const int m = t >> 3;
  const int pq = (t & 7) * 8;
  float4 v0 = make_float4(0.f, 0.f, 0.f, 0.f), v1 = v0;
#pragma unroll
  for (int w = 0; w < 4; ++w) {
    float4 a = *(float4*)&red[w * 2048 + m * 64 + pq];
    float4 c = *(float4*)&red[w * 2048 + m * 64 + pq + 4];
    v0.x += a.x; v0.y += a.y; v0.z += a.z; v0.w += a.w;
    v1.x += c.x; v1.y += c.y; v1.z += c.z; v1.w += c.w;
  }
  if (m < OC) {
    float bo = b_off[m];
    v0.x += bo; v0.y += bo; v0.z += bo; v0.w += bo;
    v1.x += bo; v1.y += bo; v1.z += bo; v1.w += bo;
    float* op = off_ws + ((size_t)b * OC + m) * HW + h * WW + pq;
    *(float4*)op = v0;
    *(float4*)(op + 4) = v1;
  }
}

// ---------------- Kernel B: g8-planar gather MFMA GEMM + fused BN epilogue ----------------
// Main loop = round-6 merged body (best measured). Epilogue: per-channel
// stats atomics -> software grid barrier (all 512 blocks co-resident:
// 2/CU needed, >=4/CU capacity at 64 VGPR / 16KB LDS) -> agent-scope stats
// read -> normalize acc in-register -> single out write. bn_kernel deleted.
__global__ __launch_bounds__(512, 4) void gemm_kernel(
    const unsigned short* __restrict__ xt, const unsigned short* __restrict__ wTb,
    const float* __restrict__ off_ws, const float* __restrict__ bias,
    const float* __restrict__ gamma, const float* __restrict__ beta,
    float* __restrict__ out, float* __restrict__ stats,
    unsigned int* __restrict__ bar) {
  __shared__ unsigned short s_b[2][4096];   // [buf][oct(8)][px(64)][8]
  const int t = threadIdx.x;
  const int lane = t & 63;
  const int wv = t >> 6;               // 0..7
  const int b = blockIdx.x & 7;
  const int h = blockIdx.x >> 3;
  const int p0 = h * 64;
  const int col = t & 63;              // gather pixel (column in row h)
  const int oct = t >> 6;              // channel octet (8ch) within 64-chunk
  const int fr = lane & 15, fq = lane >> 4;
  const unsigned short* xtb = xt + (size_t)b * 32 * HW * 8;
  const float* offp = off_ws + (size_t)b * OC * HW + p0 + col;

  int cofs[4];       // corner byte offsets within a g8 plane: (cy*WW+cx)*16
  f32x2 qw2[4];      // bilinear weights, broadcast into both f32 lanes

  auto calc = [&](int kk, float dy, float dx) {
    float py = (float)(kk / 3 - 1 + h) + dy;
    float pxx = (float)(kk % 3 - 1 + col) + dx;
    float y0f = floorf(py), x0f = floorf(pxx);
    float fy = py - y0f, fx = pxx - x0f;
    int y0 = (int)y0f, x0 = (int)x0f;
    int y1 = y0 + 1, x1 = x0 + 1;
    bool vy0 = (y0 >= 0) && (y0 < HH), vy1 = (y1 >= 0) && (y1 < HH);
    bool vx0 = (x0 >= 0) && (x0 < WW), vx1 = (x1 >= 0) && (x1 < WW);
    int cy0 = min(max(y0, 0), HH - 1), cy1 = min(max(y1, 0), HH - 1);
    int cx0 = min(max(x0, 0), WW - 1), cx1 = min(max(x1, 0), WW - 1);
    float q0 = (vy0 && vx0) ? (1.f - fy) * (1.f - fx) : 0.f;
    float q1 = (vy0 && vx1) ? (1.f - fy) * fx : 0.f;
    float q2 = (vy1 && vx0) ? fy * (1.f - fx) : 0.f;
    float q3 = (vy1 && vx1) ? fy * fx : 0.f;
    cofs[0] = (cy0 * WW + cx0) * 16;  qw2[0][0] = q0; qw2[0][1] = q0;
    cofs[1] = (cy0 * WW + cx1) * 16;  qw2[1][0] = q1; qw2[1][1] = q1;
    cofs[2] = (cy1 * WW + cx0) * 16;  qw2[2][0] = q2; qw2[2][1] = q2;
    cofs[3] = (cy1 * WW + cx1) * 16;  qw2[3][0] = q3; qw2[3][1] = q3;
  };

  s16x8 g[4];        // corner data for the in-flight target iter

  auto gather = [&](int chunk64) {
    const char* bp = (const char*)xtb + (((size_t)(chunk64 * 8 + oct)) << 16);
#pragma unroll
    for (int k = 0; k < 4; ++k)
      __builtin_memcpy(&g[k], bp + cofs[k], 16);
  };

  auto combine_write = [&](int buf) {
    u32x4 vout;
#pragma unroll
    for (int jp = 0; jp < 4; ++jp) {
      f32x2 a = {0.f, 0.f};
#pragma unroll
      for (int k = 0; k < 4; ++k) {
        unsigned int pr = ((const unsigned int*)&g[k])[jp];
        f32x2 xv;
        xv[0] = __uint_as_float(pr << 16);
        xv[1] = __uint_as_float(pr & 0xffff0000u);
        a = __builtin_elementwise_fma(qw2[k], xv, a);
      }
      unsigned int packed;
      asm("v_cvt_pk_bf16_f32 %0, %1, %2" : "=v"(packed) : "v"(a[0]), "v"(a[1]));
      vout[jp] = packed;
    }
    *(u32x4*)&s_b[buf][(oct * 64 + col) * 8] = vout;
  };

  auto load_a = [&](int iter, s16x8 af[2][2]) {
#pragma unroll
    for (int ks = 0; ks < 2; ++ks) {
      const unsigned short* ap =
          wTb + (((size_t)(iter * 2 + ks) * 4 + fq) * 256 + wv * 32 + fr) * 8;
#pragma unroll
      for (int i = 0; i < 2; ++i)
        af[ks][i] = *(const s16x8*)(ap + (size_t)i * 16 * 8);
    }
  };

  f32x4 acc[2][4] = {};
  s16x8 afE[2][2], afO[2][2];
  float dyp, dxp;

  {
    float dy0 = offp[0];
    float dx0 = offp[HW];
    calc(0, dy0, dx0);
    dyp = offp[2 * HW];
    dxp = offp[3 * HW];
    gather(0);
    load_a(0, afE);
    combine_write(0);
  }
  asm volatile("s_waitcnt lgkmcnt(0)" ::: "memory");
  __builtin_amdgcn_s_barrier();

#define GBODY(I, AFC, AFN, CUR)                                                \
  {                                                                            \
    const int nx1 = (I) + 1;                                                   \
    if (nx1 < 36) {                                                            \
      if ((nx1 & 3) == 0) {                                                    \
        const int kkc = nx1 >> 2;                                              \
        calc(kkc, dyp, dxp);                                                   \
        const int kkn = kkc + 1;                                               \
        if (kkn < 9) {                                                         \
          dyp = offp[(size_t)(2 * kkn) * HW];                                  \
          dxp = offp[(size_t)(2 * kkn + 1) * HW];                              \
        }                                                                      \
      }                                                                        \
      gather(nx1 & 3);                                                         \
      load_a(nx1, AFN);                                                        \
    }                                                                          \
    __builtin_amdgcn_s_setprio(1);                                             \
    _Pragma("unroll")                                                          \
    for (int ks = 0; ks < 2; ++ks)                                             \
      _Pragma("unroll")                                                        \
      for (int jj = 0; jj < 4; ++jj) {                                         \
        s16x8 bfr = *(const s16x8*)&s_b[CUR][((ks * 4 + fq) * 64 + jj * 16 + fr) * 8]; \
        _Pragma("unroll")                                                      \
        for (int ii = 0; ii < 2; ++ii)                                         \
          acc[ii][jj] = __builtin_amdgcn_mfma_f32_16x16x32_bf16(               \
              AFC[ks][ii], bfr, acc[ii][jj], 0, 0, 0);                         \
      }                                                                        \
    __builtin_amdgcn_s_setprio(0);                                             \
    if (nx1 < 36) {                                                            \
      combine_write((CUR) ^ 1);                                                \
      asm volatile("s_waitcnt lgkmcnt(0)" ::: "memory");                       \
      __builtin_amdgcn_s_barrier();                                            \
    }                                                                          \
  }

  for (int m = 0; m < 18; ++m) {
    const int i0 = 2 * m;
    GBODY(i0, afE, afO, 0)
    GBODY(i0 + 1, afO, afE, 1)
  }
#undef GBODY

  // ---- stats accumulation (pre-barrier) ----
#pragma unroll
  for (int i = 0; i < 2; ++i)
#pragma unroll
    for (int rg = 0; rg < 4; ++rg) {
      int o = wv * 32 + i * 16 + fq * 4 + rg;
      float bv = bias[o];
      float s = 0.f, s2 = 0.f;
#pragma unroll
      for (int j = 0; j < 4; ++j) {
        float val = acc[i][j][rg] + bv;
        s += val; s2 += val * val;
      }
#pragma unroll
      for (int m2 = 1; m2 < 16; m2 <<= 1) {
        s += __shfl_xor(s, m2);
        s2 += __shfl_xor(s2, m2);
      }
      if (fr == 0) {
        atomicAdd(&stats[o], s);
        atomicAdd(&stats[COUT + o], s2);
      }
    }

  // ---- software grid barrier (monotonic count, counter never overwritten) ----
  __syncthreads();                    // drains this block's atomics (vmcnt 0)
  if (t == 0) {
    atomicAdd(bar, 1u);
    while (atomicOr(bar, 0u) < 512u) __builtin_amdgcn_s_sleep(2);
  }
  __syncthreads();

  // ---- stage final stats to LDS (agent-scope coherent loads), normalize, write ----
  float* s_stats = (float*)s_b;
  s_stats[t] = __hip_atomic_load(&stats[t], __ATOMIC_RELAXED, __HIP_MEMORY_SCOPE_AGENT);
  __syncthreads();
  const float inv_n = 1.f / (float)(BN_ * HW);
#pragma unroll
  for (int i = 0; i < 2; ++i)
#pragma unroll
    for (int rg = 0; rg < 4; ++rg) {
      int o = wv * 32 + i * 16 + fq * 4 + rg;
      float mean = s_stats[o] * inv_n;
      float var = s_stats[COUT + o] * inv_n - mean * mean;
      float sc = gamma[o] * rsqrtf(var + EPS);
      float sh = beta[o] - mean * sc + bias[o] * sc;   // fold bias into shift
      float* op = out + ((size_t)(b * COUT + o)) * HW + p0 + fr;
#pragma unroll
      for (int j = 0; j < 4; ++j)
        op[j * 16] = fmaxf(fmaf(acc[i][j][rg], sc, sh), 0.f);
    }
}

extern "C" void kernel_launch(void* const* d_in, const int* in_sizes, int n_in,
                              void* d_out, int out_size, void* d_ws, size_t ws_size,
                              hipStream_t stream) {
  const float* x     = (const float*)d_in[0];
  const float* w_off = (const float*)d_in[1];
  const float* b_off = (const float*)d_in[2];
  const float* w     = (const float*)d_in[3];
  const float* bias  = (const float*)d_in[4];
  const float* gamma = (const float*)d_in[5];
  const float* beta  = (const float*)d_in[6];
  float* out = (float*)d_out;
  float* ws = (float*)d_ws;
  float* off_ws = ws + OFF_WS;
  unsigned short* wTb = (unsigned short*)(ws + WTB_WS);
  unsigned short* wob = (unsigned short*)(ws + WOB_WS);
  float* stats = ws + ST_WS;
  unsigned short* xt = (unsigned short*)(ws + XT_WS);
  // barrier counter in wob zero-padding (ki=71, m=31, g=3, j=0..1):
  // shorts 71*1024 + 1016.. -> 4-byte aligned, written 0 by prep each launch.
  unsigned int* bar = (unsigned int*)(wob + (size_t)71 * 1024 + 1016);

  xpose_kernel<<<dim3(64, 4, 8), 256, 0, stream>>>(x, xt);
  prep_kernel<<<72, 256, 0, stream>>>(w_off, w, wob, wTb, stats);
  offset_kernel<<<512, 256, 0, stream>>>(xt, wob, b_off, off_ws);
  gemm_kernel<<<512, 512, 0, stream>>>(xt, wTb, off_ws, bias, gamma, beta, out, stats, bar);
}

// Round 9
// 213.725 us; speedup vs baseline: 1.0539x; 1.0539x over previous
//
#include <hip/hip_runtime.h>
#include <math.h>

#define BN_ 8
#define CIN 256
#define COUT 256
#define HH 64
#define WW 64
#define HW 4096
#define KK 9
#define OC 18
#define EPS 1e-5f
#define NTOT (BN_ * COUT * HW)

// ws layout (float units):
//   off_ws region now UNUSED (offset conv fused into gemm prologue)
//   wTb:    bf16 [72][4][256][8] shorts = 294912 floats (main GEMM A image)
//   wob:    bf16 [72][4][32][8] shorts  = 36864 floats  (offset-conv A image)
//   stats:  [2][COUT]                   = 512 floats
//   xt:     bf16 [B][32][HW][8] shorts  = 4194304 floats (g8-planar x)
#define OFF_WS 0
#define WTB_WS 589824
#define WOB_WS 884736
#define ST_WS  921600
#define XT_WS  922112

typedef float f32x4 __attribute__((ext_vector_type(4)));
typedef float f32x2 __attribute__((ext_vector_type(2)));
typedef short s16x8 __attribute__((ext_vector_type(8)));
typedef unsigned int u32x4 __attribute__((ext_vector_type(4)));

__device__ __forceinline__ unsigned short f2bf(float f) {
  unsigned int u = __float_as_uint(f);
  unsigned int r = (u + 0x7fffu + ((u >> 16) & 1u)) >> 16;  // RNE
  return (unsigned short)r;
}
__device__ __forceinline__ float bf2f(short s) {
  return __uint_as_float(((unsigned int)(unsigned short)s) << 16);
}

// ---------------- Kernel T: transpose x -> xt[b][g8][p][8] bf16 ----------------
__global__ __launch_bounds__(256) void xpose_kernel(
    const float* __restrict__ x, unsigned short* __restrict__ xt) {
  __shared__ float s[64][65];
  const int t = threadIdx.x;
  const int p0 = blockIdx.x * 64;
  const int c0 = blockIdx.y * 64;
  const int b  = blockIdx.z;
  const float* xb = x + ((size_t)b * CIN + c0) * HW + p0;
#pragma unroll
  for (int pass = 0; pass < 4; ++pass) {
    int cr = pass * 16 + (t >> 4);
    int ps = (t & 15) * 4;
    float4 v = *(const float4*)(xb + (size_t)cr * HW + ps);
    s[ps + 0][cr] = v.x; s[ps + 1][cr] = v.y; s[ps + 2][cr] = v.z; s[ps + 3][cr] = v.w;
  }
  __syncthreads();
  unsigned short* xo = xt + (size_t)b * 32 * HW * 8;
#pragma unroll
  for (int r = 0; r < 2; ++r) {
    int flat = r * 256 + t;
    int pr = flat >> 3, sub = flat & 7;
    int g8 = (c0 >> 3) + sub;
    s16x8 v;
#pragma unroll
    for (int j = 0; j < 8; ++j) v[j] = (short)f2bf(s[pr][sub * 8 + j]);
    *(s16x8*)(xo + ((size_t)g8 * HW + p0 + pr) * 8) = v;
  }
}

// ---------------- Kernel P: pack w_off + w, zero stats (merged prep) ----------------
__global__ __launch_bounds__(256) void prep_kernel(
    const float* __restrict__ w_off, const float* __restrict__ w,
    unsigned short* __restrict__ wob, unsigned short* __restrict__ wTb,
    float* __restrict__ stats) {
  const int kb = blockIdx.x;          // 0..71
  const int kk = kb >> 3;
  const int c0 = (kb & 7) << 5;
  const int t = threadIdx.x;
  if (kb == 71) { stats[t] = 0.f; stats[256 + t] = 0.f; }
  // w_off pack (M=32 pad)
#pragma unroll
  for (int r = 0; r < 4; ++r) {
    int e = r * 256 + t;              // g*256 + m*8 + j
    int g = e >> 8, m = (e >> 3) & 31, j = e & 7;
    int c = c0 + g * 8 + j;
    unsigned short v = 0;
    if (m < OC) v = f2bf(w_off[((size_t)m * CIN + c) * 9 + kk]);
    wob[(size_t)kb * 1024 + e] = v;
  }
  // w pack (k-major)
#pragma unroll
  for (int g = 0; g < 4; ++g)
#pragma unroll
    for (int j = 0; j < 8; ++j) {
      int c = c0 + g * 8 + j;
      wTb[(((size_t)kb * 4 + g) * 256 + t) * 8 + j] =
          f2bf(w[((size_t)t * CIN + c) * 9 + kk]);
    }
}

// ---------------- Kernel B: fused offset-conv + gather MFMA GEMM + stats ----------------
// Per block (b,h): the offset conv for row h is computed as a PROLOGUE
// (8-way K-split, 9 steps/wave, 2-deep pipelined fetch), reduced across
// waves in LDS, and kept in s_off[18][64] — the old offset_kernel dispatch,
// off_ws traffic, and the inter-dispatch global sync are all deleted
// (producer block == consumer block, so no cross-block dependency exists).
// Main loop + epilogue = round-6 body (best measured, 100.9us).
// LDS: conv sb 32KB / red 64KB (dead after) -> s_b 16KB aliases red;
// s_off at +64KB. Total 72KB -> 2 blocks/CU.
__global__ __launch_bounds__(512, 4) void gemm_kernel(
    const unsigned short* __restrict__ xt, const unsigned short* __restrict__ wTb,
    const unsigned short* __restrict__ wob, const float* __restrict__ b_off,
    const float* __restrict__ bias, float* __restrict__ out,
    float* __restrict__ stats) {
  __shared__ __align__(16) char lds[73728];   // 64KB red/conv + 8KB s_off
  const int t = threadIdx.x;
  const int lane = t & 63;
  const int wv = t >> 6;               // 0..7
  const int b = blockIdx.x & 7;
  const int h = blockIdx.x >> 3;
  const int p0 = h * 64;
  const int col = t & 63;              // gather pixel (column in row h)
  const int oct = t >> 6;              // channel octet (8ch) within 64-chunk
  const int fr = lane & 15, fq = lane >> 4;
  const unsigned short* xtb = xt + (size_t)b * 32 * HW * 8;
  float* s_off = (float*)(lds + 65536);          // [32][64] f32 (rows 0..17 used)
  unsigned short (*s_b)[4096] = (unsigned short(*)[4096])lds;  // aliases red

  // ================= offset-conv prologue =================
  {
    unsigned short* sb = (unsigned short*)lds + wv * 2048;  // wave-private 4KB
    f32x4 acc_o[2][4] = {};

    auto fetch = [&](int s, s16x8* V, s16x8* AF) {
      const int ki = wv * 9 + s;                 // K-split: 8 waves x 9 steps
      const int kk = ki >> 3, cc0g = (ki & 7) << 2;
      const int ky = kk / 3 - 1, kx = kk % 3 - 1;
      const int y = h + ky;
      const int xcol = lane + kx;
      const bool ok = (y >= 0) && (y < HH) && (xcol >= 0) && (xcol < WW);
      const int pix = y * WW + xcol;
#pragma unroll
      for (int g = 0; g < 4; ++g) {
        s16x8 v = {0, 0, 0, 0, 0, 0, 0, 0};
        if (ok)
          __builtin_memcpy(&v, (const char*)xtb + (((size_t)(cc0g + g)) << 16) + (size_t)pix * 16, 16);
        V[g] = v;
      }
      const unsigned short* ap = wob + (size_t)ki * 1024;
#pragma unroll
      for (int i = 0; i < 2; ++i)
        AF[i] = *(const s16x8*)&ap[(fq * 32 + i * 16 + fr) * 8];
    };

    s16x8 VE[4], VO[4], afE2[2], afO2[2];
    fetch(0, VE, afE2);

#define OBODY(S, VC, VN, AFC, AFN)                                             \
    {                                                                          \
      _Pragma("unroll")                                                        \
      for (int g = 0; g < 4; ++g)                                              \
        *(s16x8*)&sb[(g * 64 + lane) * 8] = VC[g];                             \
      if ((S) + 1 < 9) fetch((S) + 1, VN, AFN);                                \
      s16x8 bf[4];                                                             \
      _Pragma("unroll")                                                        \
      for (int jn = 0; jn < 4; ++jn)                                           \
        bf[jn] = *(const s16x8*)&sb[(fq * 64 + jn * 16 + fr) * 8];             \
      _Pragma("unroll")                                                        \
      for (int i = 0; i < 2; ++i)                                              \
        _Pragma("unroll")                                                      \
        for (int jn = 0; jn < 4; ++jn)                                         \
          acc_o[i][jn] = __builtin_amdgcn_mfma_f32_16x16x32_bf16(              \
              AFC[i], bf[jn], acc_o[i][jn], 0, 0, 0);                          \
    }

    for (int sp = 0; sp < 4; ++sp) {
      OBODY(2 * sp, VE, VO, afE2, afO2)
      OBODY(2 * sp + 1, VO, VE, afO2, afE2)
    }
    OBODY(8, VE, VO, afE2, afO2)
#undef OBODY

    __syncthreads();                  // sb dead; red region takes over
    float* red = (float*)lds;
#pragma unroll
    for (int i = 0; i < 2; ++i)
#pragma unroll
      for (int jn = 0; jn < 4; ++jn)
#pragma unroll
        for (int rg = 0; rg < 4; ++rg)
          red[wv * 2048 + (i * 16 + fq * 4 + rg) * 64 + jn * 16 + fr] = acc_o[i][jn][rg];
    __syncthreads();

    // 512-thread reduction: 2048 outputs, float4 per thread, + b_off
    const int e4 = t * 4;
    const int m = e4 >> 6;            // offset channel row (0..31)
    float4 v = make_float4(0.f, 0.f, 0.f, 0.f);
#pragma unroll
    for (int w = 0; w < 8; ++w) {
      float4 a = *(float4*)&red[w * 2048 + e4];
      v.x += a.x; v.y += a.y; v.z += a.z; v.w += a.w;
    }
    float bo = (m < OC) ? b_off[m] : 0.f;
    v.x += bo; v.y += bo; v.z += bo; v.w += bo;
    *(float4*)&s_off[e4] = v;
    __syncthreads();                  // s_off ready; red dead -> s_b reusable
  }

  // ================= main gather-GEMM loop (round-6 body) =================
  int cofs[4];       // corner byte offsets within a g8 plane: (cy*WW+cx)*16
  f32x2 qw2[4];      // bilinear weights, broadcast into both f32 lanes

  auto calc = [&](int kk) {
    float dy = s_off[(2 * kk) * 64 + col];
    float dx = s_off[(2 * kk + 1) * 64 + col];
    float py = (float)(kk / 3 - 1 + h) + dy;
    float pxx = (float)(kk % 3 - 1 + col) + dx;
    float y0f = floorf(py), x0f = floorf(pxx);
    float fy = py - y0f, fx = pxx - x0f;
    int y0 = (int)y0f, x0 = (int)x0f;
    int y1 = y0 + 1, x1 = x0 + 1;
    bool vy0 = (y0 >= 0) && (y0 < HH), vy1 = (y1 >= 0) && (y1 < HH);
    bool vx0 = (x0 >= 0) && (x0 < WW), vx1 = (x1 >= 0) && (x1 < WW);
    int cy0 = min(max(y0, 0), HH - 1), cy1 = min(max(y1, 0), HH - 1);
    int cx0 = min(max(x0, 0), WW - 1), cx1 = min(max(x1, 0), WW - 1);
    float q0 = (vy0 && vx0) ? (1.f - fy) * (1.f - fx) : 0.f;
    float q1 = (vy0 && vx1) ? (1.f - fy) * fx : 0.f;
    float q2 = (vy1 && vx0) ? fy * (1.f - fx) : 0.f;
    float q3 = (vy1 && vx1) ? fy * fx : 0.f;
    cofs[0] = (cy0 * WW + cx0) * 16;  qw2[0][0] = q0; qw2[0][1] = q0;
    cofs[1] = (cy0 * WW + cx1) * 16;  qw2[1][0] = q1; qw2[1][1] = q1;
    cofs[2] = (cy1 * WW + cx0) * 16;  qw2[2][0] = q2; qw2[2][1] = q2;
    cofs[3] = (cy1 * WW + cx1) * 16;  qw2[3][0] = q3; qw2[3][1] = q3;
  };

  s16x8 g[4];        // corner data for the in-flight target iter

  auto gather = [&](int chunk64) {
    const char* bp = (const char*)xtb + (((size_t)(chunk64 * 8 + oct)) << 16);
#pragma unroll
    for (int k = 0; k < 4; ++k)
      __builtin_memcpy(&g[k], bp + cofs[k], 16);
  };

  auto combine_write = [&](int buf) {
    u32x4 vout;
#pragma unroll
    for (int jp = 0; jp < 4; ++jp) {
      f32x2 a = {0.f, 0.f};
#pragma unroll
      for (int k = 0; k < 4; ++k) {
        unsigned int pr = ((const unsigned int*)&g[k])[jp];
        f32x2 xv;
        xv[0] = __uint_as_float(pr << 16);
        xv[1] = __uint_as_float(pr & 0xffff0000u);
        a = __builtin_elementwise_fma(qw2[k], xv, a);
      }
      unsigned int packed;
      asm("v_cvt_pk_bf16_f32 %0, %1, %2" : "=v"(packed) : "v"(a[0]), "v"(a[1]));
      vout[jp] = packed;
    }
    *(u32x4*)&s_b[buf][(oct * 64 + col) * 8] = vout;
  };

  auto load_a = [&](int iter, s16x8 af[2][2]) {
#pragma unroll
    for (int ks = 0; ks < 2; ++ks) {
      const unsigned short* ap =
          wTb + (((size_t)(iter * 2 + ks) * 4 + fq) * 256 + wv * 32 + fr) * 8;
#pragma unroll
      for (int i = 0; i < 2; ++i)
        af[ks][i] = *(const s16x8*)(ap + (size_t)i * 16 * 8);
    }
  };

  f32x4 acc[2][4] = {};
  s16x8 afE[2][2], afO[2][2];

  {
    calc(0);
    gather(0);
    load_a(0, afE);
    combine_write(0);
  }
  asm volatile("s_waitcnt lgkmcnt(0)" ::: "memory");
  __builtin_amdgcn_s_barrier();

#define GBODY(I, AFC, AFN, CUR)                                                \
  {                                                                            \
    const int nx1 = (I) + 1;                                                   \
    if (nx1 < 36) {                                                            \
      if ((nx1 & 3) == 0) calc(nx1 >> 2);                                      \
      gather(nx1 & 3);                                                         \
      load_a(nx1, AFN);                                                        \
    }                                                                          \
    __builtin_amdgcn_s_setprio(1);                                             \
    _Pragma("unroll")                                                          \
    for (int ks = 0; ks < 2; ++ks)                                             \
      _Pragma("unroll")                                                        \
      for (int jj = 0; jj < 4; ++jj) {                                         \
        s16x8 bfr = *(const s16x8*)&s_b[CUR][((ks * 4 + fq) * 64 + jj * 16 + fr) * 8]; \
        _Pragma("unroll")                                                      \
        for (int ii = 0; ii < 2; ++ii)                                         \
          acc[ii][jj] = __builtin_amdgcn_mfma_f32_16x16x32_bf16(               \
              AFC[ks][ii], bfr, acc[ii][jj], 0, 0, 0);                         \
      }                                                                        \
    __builtin_amdgcn_s_setprio(0);                                             \
    if (nx1 < 36) {                                                            \
      combine_write((CUR) ^ 1);                                                \
      asm volatile("s_waitcnt lgkmcnt(0)" ::: "memory");                       \
      __builtin_amdgcn_s_barrier();                                            \
    }                                                                          \
  }

  for (int m = 0; m < 18; ++m) {
    const int i0 = 2 * m;
    GBODY(i0, afE, afO, 0)
    GBODY(i0 + 1, afO, afE, 1)
  }
#undef GBODY

  // epilogue: + bias, store, fused per-channel sum/sumsq
#pragma unroll
  for (int i = 0; i < 2; ++i) {
#pragma unroll
    for (int rg = 0; rg < 4; ++rg) {
      int o = wv * 32 + i * 16 + fq * 4 + rg;
      float bv = bias[o];
      float* op = out + ((size_t)(b * COUT + o)) * HW + p0 + fr;
      float s = 0.f, s2 = 0.f;
#pragma unroll
      for (int j = 0; j < 4; ++j) {
        float val = acc[i][j][rg] + bv;
        op[j * 16] = val;
        s += val; s2 += val * val;
      }
#pragma unroll
      for (int m2 = 1; m2 < 16; m2 <<= 1) {
        s += __shfl_xor(s, m2);
        s2 += __shfl_xor(s2, m2);
      }
      if (fr == 0) {
        atomicAdd(&stats[o], s);
        atomicAdd(&stats[COUT + o], s2);
      }
    }
  }
}

// ---------------- Kernel D: normalize + ReLU in-place ----------------
__global__ __launch_bounds__(256) void bn_kernel(
    float* __restrict__ out, const float* __restrict__ stats,
    const float* __restrict__ gamma, const float* __restrict__ beta) {
  int i4 = (blockIdx.x * 256 + threadIdx.x) * 4;
  int o = (i4 >> 12) & (COUT - 1);
  const float inv_n = 1.f / (float)(BN_ * HW);
  float mean = stats[o] * inv_n;
  float var = stats[COUT + o] * inv_n - mean * mean;
  float sc = gamma[o] * rsqrtf(var + EPS);
  float sh = beta[o] - mean * sc;
  float4 v = *(float4*)(out + i4);
  v.x = fmaxf(fmaf(v.x, sc, sh), 0.f);
  v.y = fmaxf(fmaf(v.y, sc, sh), 0.f);
  v.z = fmaxf(fmaf(v.z, sc, sh), 0.f);
  v.w = fmaxf(fmaf(v.w, sc, sh), 0.f);
  *(float4*)(out + i4) = v;
}

extern "C" void kernel_launch(void* const* d_in, const int* in_sizes, int n_in,
                              void* d_out, int out_size, void* d_ws, size_t ws_size,
                              hipStream_t stream) {
  const float* x     = (const float*)d_in[0];
  const float* w_off = (const float*)d_in[1];
  const float* b_off = (const float*)d_in[2];
  const float* w     = (const float*)d_in[3];
  const float* bias  = (const float*)d_in[4];
  const float* gamma = (const float*)d_in[5];
  const float* beta  = (const float*)d_in[6];
  float* out = (float*)d_out;
  float* ws = (float*)d_ws;
  unsigned short* wTb = (unsigned short*)(ws + WTB_WS);
  unsigned short* wob = (unsigned short*)(ws + WOB_WS);
  float* stats = ws + ST_WS;
  unsigned short* xt = (unsigned short*)(ws + XT_WS);

  xpose_kernel<<<dim3(64, 4, 8), 256, 0, stream>>>(x, xt);
  prep_kernel<<<72, 256, 0, stream>>>(w_off, w, wob, wTb, stats);
  gemm_kernel<<<512, 512, 0, stream>>>(xt, wTb, wob, b_off, bias, out, stats);
  bn_kernel<<<NTOT / 1024, 256, 0, stream>>>(out, stats, gamma, beta);
}

// Round 10
// 200.772 us; speedup vs baseline: 1.1219x; 1.0645x over previous
//
#include <hip/hip_runtime.h>
#include <math.h>

#define BN_ 8
#define CIN 256
#define COUT 256
#define HH 64
#define WW 64
#define HW 4096
#define KK 9
#define OC 18
#define EPS 1e-5f
#define NTOT (BN_ * COUT * HW)

// ws layout (float units):
//   wTb:    bf16 [72][4][256][8] shorts = 294912 floats (main GEMM A image)
//   wob:    bf16 [72][4][32][8] shorts  = 36864 floats  (offset-conv A image)
//   stats:  [2][COUT]                   = 512 floats
//   xt:     bf16 [B][32][HW][8] shorts  = 4194304 floats (g8-planar x)
#define WTB_WS 589824
#define WOB_WS 884736
#define ST_WS  921600
#define XT_WS  922112

typedef float f32x4 __attribute__((ext_vector_type(4)));
typedef float f32x2 __attribute__((ext_vector_type(2)));
typedef short s16x8 __attribute__((ext_vector_type(8)));
typedef unsigned int u32x4 __attribute__((ext_vector_type(4)));

__device__ __forceinline__ unsigned short f2bf(float f) {
  unsigned int u = __float_as_uint(f);
  unsigned int r = (u + 0x7fffu + ((u >> 16) & 1u)) >> 16;  // RNE
  return (unsigned short)r;
}
__device__ __forceinline__ float bf2f(short s) {
  return __uint_as_float(((unsigned int)(unsigned short)s) << 16);
}

// ---------------- Kernel T: transpose x -> xt[b][g8][p][8] bf16 ----------------
__global__ __launch_bounds__(256) void xpose_kernel(
    const float* __restrict__ x, unsigned short* __restrict__ xt) {
  __shared__ float s[64][65];
  const int t = threadIdx.x;
  const int p0 = blockIdx.x * 64;
  const int c0 = blockIdx.y * 64;
  const int b  = blockIdx.z;
  const float* xb = x + ((size_t)b * CIN + c0) * HW + p0;
#pragma unroll
  for (int pass = 0; pass < 4; ++pass) {
    int cr = pass * 16 + (t >> 4);
    int ps = (t & 15) * 4;
    float4 v = *(const float4*)(xb + (size_t)cr * HW + ps);
    s[ps + 0][cr] = v.x; s[ps + 1][cr] = v.y; s[ps + 2][cr] = v.z; s[ps + 3][cr] = v.w;
  }
  __syncthreads();
  unsigned short* xo = xt + (size_t)b * 32 * HW * 8;
#pragma unroll
  for (int r = 0; r < 2; ++r) {
    int flat = r * 256 + t;
    int pr = flat >> 3, sub = flat & 7;
    int g8 = (c0 >> 3) + sub;
    s16x8 v;
#pragma unroll
    for (int j = 0; j < 8; ++j) v[j] = (short)f2bf(s[pr][sub * 8 + j]);
    *(s16x8*)(xo + ((size_t)g8 * HW + p0 + pr) * 8) = v;
  }
}

// ---------------- Kernel P: pack w_off + w, zero stats (merged prep) ----------------
__global__ __launch_bounds__(256) void prep_kernel(
    const float* __restrict__ w_off, const float* __restrict__ w,
    unsigned short* __restrict__ wob, unsigned short* __restrict__ wTb,
    float* __restrict__ stats) {
  const int kb = blockIdx.x;          // 0..71
  const int kk = kb >> 3;
  const int c0 = (kb & 7) << 5;
  const int t = threadIdx.x;
  if (kb == 71) { stats[t] = 0.f; stats[256 + t] = 0.f; }
  // w_off pack (M=32 pad)
#pragma unroll
  for (int r = 0; r < 4; ++r) {
    int e = r * 256 + t;              // g*256 + m*8 + j
    int g = e >> 8, m = (e >> 3) & 31, j = e & 7;
    int c = c0 + g * 8 + j;
    unsigned short v = 0;
    if (m < OC) v = f2bf(w_off[((size_t)m * CIN + c) * 9 + kk]);
    wob[(size_t)kb * 1024 + e] = v;
  }
  // w pack (k-major)
#pragma unroll
  for (int g = 0; g < 4; ++g)
#pragma unroll
    for (int j = 0; j < 8; ++j) {
      int c = c0 + g * 8 + j;
      wTb[(((size_t)kb * 4 + g) * 256 + t) * 8 + j] =
          f2bf(w[((size_t)t * CIN + c) * 9 + kk]);
    }
}

// ---------------- Kernel B: fused offset-conv + gather MFMA GEMM, N=128 ----------------
// Grid 256 (b = bx&7, 128-px double-row tile hh2 = bx>>3), block 1024 = 16
// waves, M=16/wave. vs the N=64 version: A-fragment L2 transactions HALVED
// (each K64xM256 A-tile now amortized over 128 px) and total barrier events
// halved; per-thread gather/combine/calc unchanged (1024 thr = 8 oct x 128 px).
// Conv prologue: wave = (ki-group wg = wv&7) x (pixel-half = wv>>3 == row);
// two-pass LDS reduction (2 x 64KB of partials), stride-2 reduce reads kill
// the old 262K bank conflicts. LDS 80KB; 1 block/CU; launch_bounds(1024,4)
// caps VGPR at 128 (est ~100, falsifier: VGPR_Count > 128).
__global__ __launch_bounds__(1024, 4) void gemm_kernel(
    const unsigned short* __restrict__ xt, const unsigned short* __restrict__ wTb,
    const unsigned short* __restrict__ wob, const float* __restrict__ b_off,
    const float* __restrict__ bias, float* __restrict__ out,
    float* __restrict__ stats) {
  __shared__ __align__(16) char lds[81920];   // 64KB sb/red (s_b aliases) + 16KB s_off
  const int t = threadIdx.x;
  const int lane = t & 63;
  const int wv = t >> 6;               // 0..15
  const int b = blockIdx.x & 7;
  const int hh2 = blockIdx.x >> 3;     // double-row tile: rows 2*hh2, 2*hh2+1
  const int p0 = hh2 * 128;
  const int col = t & 127;             // gather pixel within 128-px tile
  const int oct = t >> 7;              // channel octet (8ch) within 64-chunk
  const int fr = lane & 15, fq = lane >> 4;
  const unsigned short* xtb = xt + (size_t)b * 32 * HW * 8;
  float* s_off = (float*)(lds + 65536);          // [32][128] f32 (rows 0..17 used)
  unsigned short (*s_b)[8192] = (unsigned short(*)[8192])lds;  // 2 x 16KB, aliases red

  // ================= offset-conv prologue =================
  {
    const int wg = wv & 7;             // ki group: ki = wg*9 + s
    const int half = wv >> 3;          // pixel half == row within tile
    const int yrow = 2 * hh2 + half;
    unsigned short* sb = (unsigned short*)lds + wv * 2048;  // wave-private 4KB
    f32x4 acc_o[2][4] = {};

    auto fetch = [&](int s, s16x8* V, s16x8* AF) {
      const int ki = wg * 9 + s;
      const int kk = ki >> 3, cc0g = (ki & 7) << 2;
      const int ky = kk / 3 - 1, kx = kk % 3 - 1;
      const int y = yrow + ky;
      const int xcol = lane + kx;
      const bool ok = (y >= 0) && (y < HH) && (xcol >= 0) && (xcol < WW);
      const int pix = y * WW + xcol;
#pragma unroll
      for (int g = 0; g < 4; ++g) {
        s16x8 v = {0, 0, 0, 0, 0, 0, 0, 0};
        if (ok)
          __builtin_memcpy(&v, (const char*)xtb + (((size_t)(cc0g + g)) << 16) + (size_t)pix * 16, 16);
        V[g] = v;
      }
      const unsigned short* ap = wob + (size_t)ki * 1024;
#pragma unroll
      for (int i = 0; i < 2; ++i)
        AF[i] = *(const s16x8*)&ap[(fq * 32 + i * 16 + fr) * 8];
    };

    s16x8 VE[4], VO[4], afE2[2], afO2[2];
    fetch(0, VE, afE2);

#define OBODY(S, VC, VN, AFC, AFN)                                             \
    {                                                                          \
      _Pragma("unroll")                                                        \
      for (int g = 0; g < 4; ++g)                                              \
        *(s16x8*)&sb[(g * 64 + lane) * 8] = VC[g];                             \
      if ((S) + 1 < 9) fetch((S) + 1, VN, AFN);                                \
      s16x8 bf[4];                                                             \
      _Pragma("unroll")                                                        \
      for (int jn = 0; jn < 4; ++jn)                                           \
        bf[jn] = *(const s16x8*)&sb[(fq * 64 + jn * 16 + fr) * 8];             \
      _Pragma("unroll")                                                        \
      for (int i = 0; i < 2; ++i)                                              \
        _Pragma("unroll")                                                      \
        for (int jn = 0; jn < 4; ++jn)                                         \
          acc_o[i][jn] = __builtin_amdgcn_mfma_f32_16x16x32_bf16(              \
              AFC[i], bf[jn], acc_o[i][jn], 0, 0, 0);                          \
    }

    for (int sp = 0; sp < 4; ++sp) {
      OBODY(2 * sp, VE, VO, afE2, afO2)
      OBODY(2 * sp + 1, VO, VE, afO2, afE2)
    }
    OBODY(8, VE, VO, afE2, afO2)
#undef OBODY

    __syncthreads();                  // sb dead; red region takes over
    float* red = (float*)lds;
    // two passes: half h's 8 wave-partials (64KB) -> reduce -> s_off cols
#pragma unroll
    for (int pass = 0; pass < 2; ++pass) {
      if (half == pass) {
#pragma unroll
        for (int i = 0; i < 2; ++i)
#pragma unroll
          for (int jn = 0; jn < 4; ++jn)
#pragma unroll
            for (int rg = 0; rg < 4; ++rg)
              red[wg * 2048 + (i * 16 + fq * 4 + rg) * 64 + jn * 16 + fr] = acc_o[i][jn][rg];
      }
      __syncthreads();
      {
        const int f2 = t * 2;          // 1024 threads x float2 = 2048 outputs
        const int m = f2 >> 6;         // offset-channel row 0..31
        f32x2 v = {0.f, 0.f};
#pragma unroll
        for (int w = 0; w < 8; ++w) {
          f32x2 a = *(f32x2*)&red[w * 2048 + f2];
          v[0] += a[0]; v[1] += a[1];
        }
        float bo = (m < OC) ? b_off[m] : 0.f;
        v[0] += bo; v[1] += bo;
        *(f32x2*)&s_off[m * 128 + pass * 64 + (f2 & 63)] = v;
      }
      __syncthreads();
    }
  }

  // ================= main gather-GEMM loop (R6 body, N=128) =================
  int cofs[4];       // corner byte offsets within a g8 plane: (cy*WW+cx)*16
  f32x2 qw2[4];      // bilinear weights, broadcast into both f32 lanes

  auto calc = [&](int kk) {
    float dy = s_off[(2 * kk) * 128 + col];
    float dx = s_off[(2 * kk + 1) * 128 + col];
    int y = 2 * hh2 + (col >> 6);
    int xx = col & 63;
    float py = (float)(kk / 3 - 1 + y) + dy;
    float pxx = (float)(kk % 3 - 1 + xx) + dx;
    float y0f = floorf(py), x0f = floorf(pxx);
    float fy = py - y0f, fx = pxx - x0f;
    int y0 = (int)y0f, x0 = (int)x0f;
    int y1 = y0 + 1, x1 = x0 + 1;
    bool vy0 = (y0 >= 0) && (y0 < HH), vy1 = (y1 >= 0) && (y1 < HH);
    bool vx0 = (x0 >= 0) && (x0 < WW), vx1 = (x1 >= 0) && (x1 < WW);
    int cy0 = min(max(y0, 0), HH - 1), cy1 = min(max(y1, 0), HH - 1);
    int cx0 = min(max(x0, 0), WW - 1), cx1 = min(max(x1, 0), WW - 1);
    float q0 = (vy0 && vx0) ? (1.f - fy) * (1.f - fx) : 0.f;
    float q1 = (vy0 && vx1) ? (1.f - fy) * fx : 0.f;
    float q2 = (vy1 && vx0) ? fy * (1.f - fx) : 0.f;
    float q3 = (vy1 && vx1) ? fy * fx : 0.f;
    cofs[0] = (cy0 * WW + cx0) * 16;  qw2[0][0] = q0; qw2[0][1] = q0;
    cofs[1] = (cy0 * WW + cx1) * 16;  qw2[1][0] = q1; qw2[1][1] = q1;
    cofs[2] = (cy1 * WW + cx0) * 16;  qw2[2][0] = q2; qw2[2][1] = q2;
    cofs[3] = (cy1 * WW + cx1) * 16;  qw2[3][0] = q3; qw2[3][1] = q3;
  };

  s16x8 g[4];        // corner data for the in-flight target iter

  auto gather = [&](int chunk64) {
    const char* bp = (const char*)xtb + (((size_t)(chunk64 * 8 + oct)) << 16);
#pragma unroll
    for (int k = 0; k < 4; ++k)
      __builtin_memcpy(&g[k], bp + cofs[k], 16);
  };

  auto combine_write = [&](int buf) {
    u32x4 vout;
#pragma unroll
    for (int jp = 0; jp < 4; ++jp) {
      f32x2 a = {0.f, 0.f};
#pragma unroll
      for (int k = 0; k < 4; ++k) {
        unsigned int pr = ((const unsigned int*)&g[k])[jp];
        f32x2 xv;
        xv[0] = __uint_as_float(pr << 16);
        xv[1] = __uint_as_float(pr & 0xffff0000u);
        a = __builtin_elementwise_fma(qw2[k], xv, a);
      }
      unsigned int packed;
      asm("v_cvt_pk_bf16_f32 %0, %1, %2" : "=v"(packed) : "v"(a[0]), "v"(a[1]));
      vout[jp] = packed;
    }
    *(u32x4*)&s_b[buf][(oct * 128 + col) * 8] = vout;
  };

  auto load_a = [&](int iter, s16x8 af[2]) {
#pragma unroll
    for (int ks = 0; ks < 2; ++ks)
      af[ks] = *(const s16x8*)&wTb[(((size_t)(iter * 2 + ks) * 4 + fq) * 256 + wv * 16 + fr) * 8];
  };

  f32x4 acc[8] = {};
  s16x8 afE[2], afO[2];

  {
    calc(0);
    gather(0);
    load_a(0, afE);
    combine_write(0);
  }
  asm volatile("s_waitcnt lgkmcnt(0)" ::: "memory");
  __builtin_amdgcn_s_barrier();

#define GBODY(I, AFC, AFN, CUR)                                                \
  {                                                                            \
    const int nx1 = (I) + 1;                                                   \
    if (nx1 < 36) {                                                            \
      if ((nx1 & 3) == 0) calc(nx1 >> 2);                                      \
      gather(nx1 & 3);                                                         \
      load_a(nx1, AFN);                                                        \
    }                                                                          \
    __builtin_amdgcn_s_setprio(1);                                             \
    _Pragma("unroll")                                                          \
    for (int ks = 0; ks < 2; ++ks)                                             \
      _Pragma("unroll")                                                        \
      for (int jj = 0; jj < 8; ++jj) {                                         \
        s16x8 bfr = *(const s16x8*)&s_b[CUR][((ks * 4 + fq) * 128 + jj * 16 + fr) * 8]; \
        acc[jj] = __builtin_amdgcn_mfma_f32_16x16x32_bf16(                     \
            AFC[ks], bfr, acc[jj], 0, 0, 0);                                   \
      }                                                                        \
    __builtin_amdgcn_s_setprio(0);                                             \
    if (nx1 < 36) {                                                            \
      combine_write((CUR) ^ 1);                                                \
      asm volatile("s_waitcnt lgkmcnt(0)" ::: "memory");                       \
      __builtin_amdgcn_s_barrier();                                            \
    }                                                                          \
  }

  for (int m = 0; m < 18; ++m) {
    const int i0 = 2 * m;
    GBODY(i0, afE, afO, 0)
    GBODY(i0 + 1, afO, afE, 1)
  }
#undef GBODY

  // epilogue: + bias, store, fused per-channel sum/sumsq
#pragma unroll
  for (int rg = 0; rg < 4; ++rg) {
    int o = wv * 16 + fq * 4 + rg;
    float bv = bias[o];
    float* op = out + ((size_t)(b * COUT + o)) * HW + p0 + fr;
    float s = 0.f, s2 = 0.f;
#pragma unroll
    for (int j = 0; j < 8; ++j) {
      float val = acc[j][rg] + bv;
      op[j * 16] = val;
      s += val; s2 += val * val;
    }
#pragma unroll
    for (int m2 = 1; m2 < 16; m2 <<= 1) {
      s += __shfl_xor(s, m2);
      s2 += __shfl_xor(s2, m2);
    }
    if (fr == 0) {
      atomicAdd(&stats[o], s);
      atomicAdd(&stats[COUT + o], s2);
    }
  }
}

// ---------------- Kernel D: normalize + ReLU in-place ----------------
__global__ __launch_bounds__(256) void bn_kernel(
    float* __restrict__ out, const float* __restrict__ stats,
    const float* __restrict__ gamma, const float* __restrict__ beta) {
  int i4 = (blockIdx.x * 256 + threadIdx.x) * 4;
  int o = (i4 >> 12) & (COUT - 1);
  const float inv_n = 1.f / (float)(BN_ * HW);
  float mean = stats[o] * inv_n;
  float var = stats[COUT + o] * inv_n - mean * mean;
  float sc = gamma[o] * rsqrtf(var + EPS);
  float sh = beta[o] - mean * sc;
  float4 v = *(float4*)(out + i4);
  v.x = fmaxf(fmaf(v.x, sc, sh), 0.f);
  v.y = fmaxf(fmaf(v.y, sc, sh), 0.f);
  v.z = fmaxf(fmaf(v.z, sc, sh), 0.f);
  v.w = fmaxf(fmaf(v.w, sc, sh), 0.f);
  *(float4*)(out + i4) = v;
}

extern "C" void kernel_launch(void* const* d_in, const int* in_sizes, int n_in,
                              void* d_out, int out_size, void* d_ws, size_t ws_size,
                              hipStream_t stream) {
  const float* x     = (const float*)d_in[0];
  const float* w_off = (const float*)d_in[1];
  const float* b_off = (const float*)d_in[2];
  const float* w     = (const float*)d_in[3];
  const float* bias  = (const float*)d_in[4];
  const float* gamma = (const float*)d_in[5];
  const float* beta  = (const float*)d_in[6];
  float* out = (float*)d_out;
  float* ws = (float*)d_ws;
  unsigned short* wTb = (unsigned short*)(ws + WTB_WS);
  unsigned short* wob = (unsigned short*)(ws + WOB_WS);
  float* stats = ws + ST_WS;
  unsigned short* xt = (unsigned short*)(ws + XT_WS);

  xpose_kernel<<<dim3(64, 4, 8), 256, 0, stream>>>(x, xt);
  prep_kernel<<<72, 256, 0, stream>>>(w_off, w, wob, wTb, stats);
  gemm_kernel<<<256, 1024, 0, stream>>>(xt, wTb, wob, b_off, bias, out, stats);
  bn_kernel<<<NTOT / 1024, 256, 0, stream>>>(out, stats, gamma, beta);
}